// Round 4
// baseline (129.855 us; speedup 1.0000x reference)
//
#include <hip/hip_runtime.h>
#include <math.h>

#define N_NODES 2000
#define E_DIM   128
#define QKV_W   384
#define LDA     36   // A-tile leading dim pad

// ---------------------------------------------------------------------------
// Kernel 1: fused prep + qkv. (unchanged from R3 — ~3 us, not the bottleneck)
// ---------------------------------------------------------------------------
__global__ __launch_bounds__(256) void prep_qkv_kernel(
    const float* __restrict__ x, const float* __restrict__ coords9,
    const float* __restrict__ ps, const float* __restrict__ pe_w,
    const float* __restrict__ pe_b, const float* __restrict__ pe_g,
    const float* __restrict__ pe_bt, const float* __restrict__ in_w,
    const float* __restrict__ in_b,
    float* __restrict__ cx_, float* __restrict__ cy_, float* __restrict__ cz_,
    float* __restrict__ qkv)
{
    __shared__ __align__(16) float As[E_DIM * LDA]; // As[c][r]
    int tid = threadIdx.x;
    int rt = blockIdx.x / 3, ct = blockIdx.x % 3;
    int rbase = rt * 32, cbase = ct * 128;
    int g = tid >> 5, lane = tid & 31;

    #pragma unroll
    for (int rr = 0; rr < 4; ++rr) {
        int rl = rr * 8 + g;
        int row = rbase + rl;
        bool vr = (row < N_NODES);
        float cx = 0.f, cy = 0.f, cz = 0.f;
        if (vr) {
            const float* c9 = coords9 + row * 9;
            cx = (c9[0] + c9[3] + c9[6]) * (1.0f / 3.0f);
            cy = (c9[1] + c9[4] + c9[7]) * (1.0f / 3.0f);
            cz = (c9[2] + c9[5] + c9[8]) * (1.0f / 3.0f);
        }
        if (ct == 0 && vr && lane == 0) { cx_[row] = cx; cy_[row] = cy; cz_[row] = cz; }

        #pragma unroll
        for (int k = 0; k < 3; ++k) {
            int c = lane + 32 * k;
            float v = vr ? (x[row * E_DIM + c] + ps[c]) : 0.f;
            As[c * LDA + rl] = v;
        }

        int j = lane;
        float h = cx * pe_w[j] + cy * pe_w[32 + j] + cz * pe_w[64 + j] + pe_b[j];
        float ge = 0.5f * h * (1.0f + erff(h * 0.7071067811865476f)); // exact GELU
        float s = ge;
        #pragma unroll
        for (int m = 16; m >= 1; m >>= 1) s += __shfl_xor(s, m);
        float mu = s * (1.0f / 32.0f);
        float d = ge - mu;
        float v2 = d * d;
        #pragma unroll
        for (int m = 16; m >= 1; m >>= 1) v2 += __shfl_xor(v2, m);
        float var = v2 * (1.0f / 32.0f);
        float y = d * (1.0f / sqrtf(var + 1e-5f)) * pe_g[j] + pe_bt[j];
        As[(96 + j) * LDA + rl] = vr ? y : 0.f;
    }
    __syncthreads();

    int cg = tid & 31, rg = tid >> 5;
    int c0 = cbase + cg * 4, r0 = rg * 4;
    float acc[4][4];
    #pragma unroll
    for (int i = 0; i < 4; ++i)
        #pragma unroll
        for (int jj = 0; jj < 4; ++jj) acc[i][jj] = 0.f;

    for (int k0 = 0; k0 < 128; k0 += 4) {
        float4 a0 = *(const float4*)&As[(k0 + 0) * LDA + r0];
        float4 a1 = *(const float4*)&As[(k0 + 1) * LDA + r0];
        float4 a2 = *(const float4*)&As[(k0 + 2) * LDA + r0];
        float4 a3 = *(const float4*)&As[(k0 + 3) * LDA + r0];
        #pragma unroll
        for (int ci = 0; ci < 4; ++ci) {
            float4 b = *(const float4*)&in_w[(c0 + ci) * E_DIM + k0];
            acc[0][ci] += a0.x * b.x + a1.x * b.y + a2.x * b.z + a3.x * b.w;
            acc[1][ci] += a0.y * b.x + a1.y * b.y + a2.y * b.z + a3.y * b.w;
            acc[2][ci] += a0.z * b.x + a1.z * b.y + a2.z * b.z + a3.z * b.w;
            acc[3][ci] += a0.w * b.x + a1.w * b.y + a2.w * b.z + a3.w * b.w;
        }
    }

    #pragma unroll
    for (int ri = 0; ri < 4; ++ri) {
        int row = rbase + r0 + ri;
        if (row < N_NODES) {
            float4 o4;
            o4.x = acc[ri][0] + in_b[c0 + 0];
            o4.y = acc[ri][1] + in_b[c0 + 1];
            o4.z = acc[ri][2] + in_b[c0 + 2];
            o4.w = acc[ri][3] + in_b[c0 + 3];
            *(float4*)&qkv[row * QKV_W + c0] = o4;
        }
    }
}

// ---------------------------------------------------------------------------
// Kernel 2: fused attn + out-proj, one block per row.
// R4: PV and proj phases now use all 256 threads (two-half split + LDS
// combine) to halve their dependent-load chains.
// ---------------------------------------------------------------------------
__device__ __forceinline__ float sanitize(float v)
{
    v = (v == v) ? v : 0.f;
    return fminf(fmaxf(v, -1e4f), 1e4f);
}

__global__ __launch_bounds__(256) void attn_proj_kernel(
    const float* __restrict__ cx_, const float* __restrict__ cy_,
    const float* __restrict__ cz_, const float* __restrict__ qkv,
    const float* __restrict__ out_w, const float* __restrict__ out_b,
    float* __restrict__ out)
{
    __shared__ unsigned int hist[256];
    __shared__ float wMin[4], wMax[4];
    __shared__ float sh_lo, sh_scale;
    __shared__ int sh_b, sh_nless, sh_sel, sh_eq;
    __shared__ int waveSum[4];
    __shared__ int topk[32];
    __shared__ int eqIdx[256];
    __shared__ unsigned int eqKey[256];
    __shared__ __align__(16) float qs[128];
    __shared__ float pr[256];
    __shared__ __align__(16) float part[256];   // two-half partials (PV, proj)
    __shared__ __align__(16) float os[128];

    int tid = threadIdx.x;
    int row = blockIdx.x;
    int lane = tid & 63, wid = tid >> 6;

    float cix = cx_[row], ciy = cy_[row], ciz = cz_[row];
    unsigned int kbits[8];
    bool valid[8];
    float lmin = __int_as_float(0x7f800000);
    float lmax = __int_as_float(0xff800000);
    {
        #pragma clang fp contract(off)  // match reference bit pattern exactly
        #pragma unroll
        for (int l = 0; l < 8; ++l) {
            int j = tid + 256 * l;
            valid[l] = (j < N_NODES);
            float key = __int_as_float(0x7f800000);
            if (valid[l]) {
                float dx = cix - cx_[j];
                float dy = ciy - cy_[j];
                float dz = ciz - cz_[j];
                float a = dx * dx;
                float b = dy * dy;
                float c = dz * dz;
                float d2 = ((a + b) + c) + 1e-20f;
                key = sqrtf(d2);
                lmin = fminf(lmin, key);
                lmax = fmaxf(lmax, key);
            }
            kbits[l] = __float_as_uint(key);
        }
    }

    #pragma unroll
    for (int m = 32; m >= 1; m >>= 1) {
        lmin = fminf(lmin, __shfl_xor(lmin, m));
        lmax = fmaxf(lmax, __shfl_xor(lmax, m));
    }
    if (lane == 0) { wMin[wid] = lmin; wMax[wid] = lmax; }
    hist[tid] = 0u;
    if (tid == 0) { sh_sel = 0; sh_eq = 0; }
    __syncthreads();
    if (tid == 0) {
        float lo = fminf(fminf(wMin[0], wMin[1]), fminf(wMin[2], wMin[3]));
        float hi = fmaxf(fmaxf(wMax[0], wMax[1]), fmaxf(wMax[2], wMax[3]));
        sh_lo = lo;
        sh_scale = 255.0f / fmaxf(hi - lo, 1e-30f);
    }
    __syncthreads();
    float lo = sh_lo, scale = sh_scale;

    #pragma unroll
    for (int l = 0; l < 8; ++l) {
        if (valid[l]) {
            float key = __uint_as_float(kbits[l]);
            int bin = (int)((key - lo) * scale);
            bin = min(max(bin, 0), 255);
            atomicAdd(&hist[bin], 1u);
        }
    }
    __syncthreads();

    int h = (int)hist[tid];
    int incl = h;
    #pragma unroll
    for (int dd = 1; dd < 64; dd <<= 1) {
        int u = __shfl_up(incl, dd);
        if (lane >= dd) incl += u;
    }
    if (lane == 63) waveSum[wid] = incl;
    __syncthreads();
    int off = 0;
    for (int w = 0; w < wid; ++w) off += waveSum[w];
    int cum = incl + off;
    if (cum >= 32 && (cum - h) < 32) {
        sh_b = tid;
        sh_nless = cum - h;
    }
    __syncthreads();

    int b = sh_b;
    int req = 32 - sh_nless;

    #pragma unroll
    for (int l = 0; l < 8; ++l) {
        if (valid[l]) {
            float key = __uint_as_float(kbits[l]);
            int bin = (int)((key - lo) * scale);
            bin = min(max(bin, 0), 255);
            int j = tid + 256 * l;
            if (bin < b) {
                int p = atomicAdd(&sh_sel, 1);
                topk[p] = j;
            } else if (bin == b) {
                int e = atomicAdd(&sh_eq, 1);
                if (e < 256) { eqIdx[e] = j; eqKey[e] = kbits[l]; }
            }
        }
    }
    if (tid < 128) qs[tid] = qkv[row * QKV_W + tid];
    __syncthreads();

    int eq = min(sh_eq, 256);
    if (tid < eq) {
        int myIdx = eqIdx[tid];
        unsigned int myKey = eqKey[tid];
        int rank = 0;
        for (int u = 0; u < eq; ++u) {
            unsigned int ku = eqKey[u];
            rank += (ku < myKey || (ku == myKey && eqIdx[u] < myIdx)) ? 1 : 0;
        }
        if (rank < req) {
            int p = atomicAdd(&sh_sel, 1);
            topk[p] = myIdx;
        }
    }
    __syncthreads();

    // ---- scores + softmax: thread = (head hh, slot j)
    {
        int hh = tid >> 5, j = tid & 31;
        int jj = topk[j];
        const float4* kp = (const float4*)&qkv[jj * QKV_W + 128 + hh * 16];
        const float4* qp = (const float4*)&qs[hh * 16];
        float s = 0.f;
        #pragma unroll
        for (int i = 0; i < 4; ++i) {
            float4 kv = kp[i], qv = qp[i];
            s += qv.x * kv.x + qv.y * kv.y + qv.z * kv.z + qv.w * kv.w;
        }
        s *= 0.25f;
        float m = s;
        #pragma unroll
        for (int msk = 16; msk >= 1; msk >>= 1) m = fmaxf(m, __shfl_xor(m, msk));
        float p = expf(s - m);
        float su = p;
        #pragma unroll
        for (int msk = 16; msk >= 1; msk >>= 1) su += __shfl_xor(su, msk);
        pr[tid] = p / su;
    }
    __syncthreads();

    // ---- o = probs @ v, all 256 threads: half = j-range split, LDS combine
    {
        int c = tid & 127, half = tid >> 7;    // c = output element, half = slot half
        int hh = c >> 4;
        int j0 = half * 16;
        float acc = 0.f;
        #pragma unroll
        for (int j = 0; j < 16; ++j) {
            int jj = topk[j0 + j];
            acc += pr[hh * 32 + j0 + j] * qkv[jj * QKV_W + 256 + c];
        }
        part[tid] = acc;
    }
    __syncthreads();
    if (tid < 128) os[tid] = part[tid] + part[tid + 128];
    __syncthreads();

    // ---- out-projection, all 256 threads: half = e-range split, LDS combine
    {
        int c = tid & 127, half = tid >> 7;
        const float* wr = out_w + c * E_DIM + half * 64;
        const float* orow = os + half * 64;
        float a = 0.f;
        #pragma unroll
        for (int e = 0; e < 64; e += 4) {
            float4 w4 = *(const float4*)&wr[e];
            float4 o4 = *(const float4*)&orow[e];
            a += o4.x * w4.x + o4.y * w4.y + o4.z * w4.z + o4.w * w4.w;
        }
        part[tid] = a;
    }
    __syncthreads();
    if (tid < 128) {
        out[row * E_DIM + tid] = sanitize(part[tid] + part[tid + 128] + out_b[tid]);
    }
}

// ---------------------------------------------------------------------------
extern "C" void kernel_launch(void* const* d_in, const int* in_sizes, int n_in,
                              void* d_out, int out_size, void* d_ws, size_t ws_size,
                              hipStream_t stream)
{
    const float* x      = (const float*)d_in[0];
    const float* coords = (const float*)d_in[1];
    const float* ps     = (const float*)d_in[2];
    const float* pe_w   = (const float*)d_in[3];
    const float* pe_b   = (const float*)d_in[4];
    const float* pe_g   = (const float*)d_in[5];
    const float* pe_bt  = (const float*)d_in[6];
    const float* in_w   = (const float*)d_in[7];
    const float* in_b   = (const float*)d_in[8];
    const float* out_w  = (const float*)d_in[9];
    const float* out_b  = (const float*)d_in[10];
    float* out = (float*)d_out;

    float* ws  = (float*)d_ws;
    float* cxp = ws;            // 2048
    float* cyp = ws + 2048;     // 2048
    float* czp = ws + 4096;     // 2048
    float* qkvb = ws + 6144;    // 2000*384

    prep_qkv_kernel<<<189, 256, 0, stream>>>(x, coords, ps, pe_w, pe_b, pe_g, pe_bt,
                                             in_w, in_b, cxp, cyp, czp, qkvb);
    attn_proj_kernel<<<2000, 256, 0, stream>>>(cxp, cyp, czp, qkvb, out_w, out_b, out);
}

// Round 5
// 122.123 us; speedup vs baseline: 1.0633x; 1.0633x over previous
//
#include <hip/hip_runtime.h>
#include <math.h>

#define N_NODES 2000
#define E_DIM   128
#define QKV_W   384
#define LDA     36   // A-tile leading dim pad

// ---------------------------------------------------------------------------
// Kernel 1: fused prep + qkv. (unchanged — ~3 us, not the bottleneck)
// ---------------------------------------------------------------------------
__global__ __launch_bounds__(256) void prep_qkv_kernel(
    const float* __restrict__ x, const float* __restrict__ coords9,
    const float* __restrict__ ps, const float* __restrict__ pe_w,
    const float* __restrict__ pe_b, const float* __restrict__ pe_g,
    const float* __restrict__ pe_bt, const float* __restrict__ in_w,
    const float* __restrict__ in_b,
    float* __restrict__ cx_, float* __restrict__ cy_, float* __restrict__ cz_,
    float* __restrict__ qkv)
{
    __shared__ __align__(16) float As[E_DIM * LDA]; // As[c][r]
    int tid = threadIdx.x;
    int rt = blockIdx.x / 3, ct = blockIdx.x % 3;
    int rbase = rt * 32, cbase = ct * 128;
    int g = tid >> 5, lane = tid & 31;

    #pragma unroll
    for (int rr = 0; rr < 4; ++rr) {
        int rl = rr * 8 + g;
        int row = rbase + rl;
        bool vr = (row < N_NODES);
        float cx = 0.f, cy = 0.f, cz = 0.f;
        if (vr) {
            const float* c9 = coords9 + row * 9;
            cx = (c9[0] + c9[3] + c9[6]) * (1.0f / 3.0f);
            cy = (c9[1] + c9[4] + c9[7]) * (1.0f / 3.0f);
            cz = (c9[2] + c9[5] + c9[8]) * (1.0f / 3.0f);
        }
        if (ct == 0 && vr && lane == 0) { cx_[row] = cx; cy_[row] = cy; cz_[row] = cz; }

        #pragma unroll
        for (int k = 0; k < 3; ++k) {
            int c = lane + 32 * k;
            float v = vr ? (x[row * E_DIM + c] + ps[c]) : 0.f;
            As[c * LDA + rl] = v;
        }

        int j = lane;
        float h = cx * pe_w[j] + cy * pe_w[32 + j] + cz * pe_w[64 + j] + pe_b[j];
        float ge = 0.5f * h * (1.0f + erff(h * 0.7071067811865476f)); // exact GELU
        float s = ge;
        #pragma unroll
        for (int m = 16; m >= 1; m >>= 1) s += __shfl_xor(s, m);
        float mu = s * (1.0f / 32.0f);
        float d = ge - mu;
        float v2 = d * d;
        #pragma unroll
        for (int m = 16; m >= 1; m >>= 1) v2 += __shfl_xor(v2, m);
        float var = v2 * (1.0f / 32.0f);
        float y = d * (1.0f / sqrtf(var + 1e-5f)) * pe_g[j] + pe_bt[j];
        As[(96 + j) * LDA + rl] = vr ? y : 0.f;
    }
    __syncthreads();

    int cg = tid & 31, rg = tid >> 5;
    int c0 = cbase + cg * 4, r0 = rg * 4;
    float acc[4][4];
    #pragma unroll
    for (int i = 0; i < 4; ++i)
        #pragma unroll
        for (int jj = 0; jj < 4; ++jj) acc[i][jj] = 0.f;

    for (int k0 = 0; k0 < 128; k0 += 4) {
        float4 a0 = *(const float4*)&As[(k0 + 0) * LDA + r0];
        float4 a1 = *(const float4*)&As[(k0 + 1) * LDA + r0];
        float4 a2 = *(const float4*)&As[(k0 + 2) * LDA + r0];
        float4 a3 = *(const float4*)&As[(k0 + 3) * LDA + r0];
        #pragma unroll
        for (int ci = 0; ci < 4; ++ci) {
            float4 b = *(const float4*)&in_w[(c0 + ci) * E_DIM + k0];
            acc[0][ci] += a0.x * b.x + a1.x * b.y + a2.x * b.z + a3.x * b.w;
            acc[1][ci] += a0.y * b.x + a1.y * b.y + a2.y * b.z + a3.y * b.w;
            acc[2][ci] += a0.z * b.x + a1.z * b.y + a2.z * b.z + a3.z * b.w;
            acc[3][ci] += a0.w * b.x + a1.w * b.y + a2.w * b.z + a3.w * b.w;
        }
    }

    #pragma unroll
    for (int ri = 0; ri < 4; ++ri) {
        int row = rbase + r0 + ri;
        if (row < N_NODES) {
            float4 o4;
            o4.x = acc[ri][0] + in_b[c0 + 0];
            o4.y = acc[ri][1] + in_b[c0 + 1];
            o4.z = acc[ri][2] + in_b[c0 + 2];
            o4.w = acc[ri][3] + in_b[c0 + 3];
            *(float4*)&qkv[row * QKV_W + c0] = o4;
        }
    }
}

// ---------------------------------------------------------------------------
// Kernel 2: fused attn + out-proj, one block per row.
// R5: reverted PV/proj to 128-thread single-chain (R4's 256-thread split
// added 2 block barriers and regressed 6us); merged the lo/scale barrier
// (all threads reduce wMin/wMax redundantly); bins cached in registers.
// ---------------------------------------------------------------------------
__device__ __forceinline__ float sanitize(float v)
{
    v = (v == v) ? v : 0.f;
    return fminf(fmaxf(v, -1e4f), 1e4f);
}

__global__ __launch_bounds__(256) void attn_proj_kernel(
    const float* __restrict__ cx_, const float* __restrict__ cy_,
    const float* __restrict__ cz_, const float* __restrict__ qkv,
    const float* __restrict__ out_w, const float* __restrict__ out_b,
    float* __restrict__ out)
{
    __shared__ unsigned int hist[256];
    __shared__ float wMin[4], wMax[4];
    __shared__ int sh_b, sh_nless, sh_sel, sh_eq;
    __shared__ int waveSum[4];
    __shared__ int topk[32];
    __shared__ int eqIdx[256];
    __shared__ unsigned int eqKey[256];
    __shared__ __align__(16) float qs[128];
    __shared__ float pr[256];
    __shared__ __align__(16) float os[128];

    int tid = threadIdx.x;
    int row = blockIdx.x;
    int lane = tid & 63, wid = tid >> 6;

    float cix = cx_[row], ciy = cy_[row], ciz = cz_[row];
    unsigned int kbits[8];
    int bins[8];
    bool valid[8];
    float lmin = __int_as_float(0x7f800000);
    float lmax = __int_as_float(0xff800000);
    {
        #pragma clang fp contract(off)  // match reference bit pattern exactly
        #pragma unroll
        for (int l = 0; l < 8; ++l) {
            int j = tid + 256 * l;
            valid[l] = (j < N_NODES);
            float key = __int_as_float(0x7f800000);
            if (valid[l]) {
                float dx = cix - cx_[j];
                float dy = ciy - cy_[j];
                float dz = ciz - cz_[j];
                float a = dx * dx;
                float b = dy * dy;
                float c = dz * dz;
                float d2 = ((a + b) + c) + 1e-20f;
                key = sqrtf(d2);
                lmin = fminf(lmin, key);
                lmax = fmaxf(lmax, key);
            }
            kbits[l] = __float_as_uint(key);
        }
    }

    // ---- block min/max (wave reduce -> LDS -> all threads reduce 4)
    #pragma unroll
    for (int m = 32; m >= 1; m >>= 1) {
        lmin = fminf(lmin, __shfl_xor(lmin, m));
        lmax = fmaxf(lmax, __shfl_xor(lmax, m));
    }
    if (lane == 0) { wMin[wid] = lmin; wMax[wid] = lmax; }
    hist[tid] = 0u;
    if (tid == 0) { sh_sel = 0; sh_eq = 0; }
    __syncthreads();
    // all threads compute lo/scale redundantly (saves a barrier)
    float lo = fminf(fminf(wMin[0], wMin[1]), fminf(wMin[2], wMin[3]));
    float hi = fmaxf(fmaxf(wMax[0], wMax[1]), fmaxf(wMax[2], wMax[3]));
    float scale = 255.0f / fmaxf(hi - lo, 1e-30f);

    // ---- linear-value histogram (monotone binning); cache bins in registers
    #pragma unroll
    for (int l = 0; l < 8; ++l) {
        int bin = 255;
        if (valid[l]) {
            float key = __uint_as_float(kbits[l]);
            bin = (int)((key - lo) * scale);
            bin = min(max(bin, 0), 255);
            atomicAdd(&hist[bin], 1u);
        }
        bins[l] = bin;
    }
    __syncthreads();

    // ---- inclusive prefix scan over 256 bins; find boundary bin
    int h = (int)hist[tid];
    int incl = h;
    #pragma unroll
    for (int dd = 1; dd < 64; dd <<= 1) {
        int u = __shfl_up(incl, dd);
        if (lane >= dd) incl += u;
    }
    if (lane == 63) waveSum[wid] = incl;
    __syncthreads();
    int off = 0;
    for (int w = 0; w < wid; ++w) off += waveSum[w];
    int cum = incl + off;
    if (cum >= 32 && (cum - h) < 32) {  // unique crossing bin (h>0 there)
        sh_b = tid;
        sh_nless = cum - h;
    }
    __syncthreads();

    int b = sh_b;
    int req = 32 - sh_nless;

    // ---- collect (bins from registers)
    #pragma unroll
    for (int l = 0; l < 8; ++l) {
        if (valid[l]) {
            int bin = bins[l];
            int j = tid + 256 * l;
            if (bin < b) {
                int p = atomicAdd(&sh_sel, 1);
                topk[p] = j;
            } else if (bin == b) {
                int e = atomicAdd(&sh_eq, 1);
                if (e < 256) { eqIdx[e] = j; eqKey[e] = kbits[l]; }
            }
        }
    }
    if (tid < 128) qs[tid] = qkv[row * QKV_W + tid];  // stage q meanwhile
    __syncthreads();

    // ---- boundary bin: exact rank on (uint32 key, index), lower index wins
    int eq = min(sh_eq, 256);
    if (tid < eq) {
        int myIdx = eqIdx[tid];
        unsigned int myKey = eqKey[tid];
        int rank = 0;
        for (int u = 0; u < eq; ++u) {
            unsigned int ku = eqKey[u];
            rank += (ku < myKey || (ku == myKey && eqIdx[u] < myIdx)) ? 1 : 0;
        }
        if (rank < req) {
            int p = atomicAdd(&sh_sel, 1);
            topk[p] = myIdx;
        }
    }
    __syncthreads();

    // ---- scores + softmax: thread = (head hh, slot j)
    {
        int hh = tid >> 5, j = tid & 31;
        int jj = topk[j];
        const float4* kp = (const float4*)&qkv[jj * QKV_W + 128 + hh * 16];
        const float4* qp = (const float4*)&qs[hh * 16];
        float s = 0.f;
        #pragma unroll
        for (int i = 0; i < 4; ++i) {
            float4 kv = kp[i], qv = qp[i];
            s += qv.x * kv.x + qv.y * kv.y + qv.z * kv.z + qv.w * kv.w;
        }
        s *= 0.25f;
        float m = s;
        #pragma unroll
        for (int msk = 16; msk >= 1; msk >>= 1) m = fmaxf(m, __shfl_xor(m, msk));
        float p = expf(s - m);
        float su = p;
        #pragma unroll
        for (int msk = 16; msk >= 1; msk >>= 1) su += __shfl_xor(su, msk);
        pr[tid] = p / su;
    }
    __syncthreads();

    // ---- o = probs @ v into LDS (128 threads, single chain — R3 form)
    if (tid < 128) {
        int hh = tid >> 4;
        float acc = 0.f;
        #pragma unroll
        for (int j = 0; j < 32; ++j) {
            int jj = topk[j];
            acc += pr[hh * 32 + j] * qkv[jj * QKV_W + 256 + tid];
        }
        os[tid] = acc;
    }
    __syncthreads();

    // ---- fused out-projection (128 threads — R3 form)
    if (tid < 128) {
        const float* wr = out_w + tid * E_DIM;
        float a = 0.f;
        #pragma unroll
        for (int e = 0; e < 128; e += 4) {
            float4 w4 = *(const float4*)&wr[e];
            float4 o4 = *(const float4*)&os[e];
            a += o4.x * w4.x + o4.y * w4.y + o4.z * w4.z + o4.w * w4.w;
        }
        out[row * E_DIM + tid] = sanitize(a + out_b[tid]);
    }
}

// ---------------------------------------------------------------------------
extern "C" void kernel_launch(void* const* d_in, const int* in_sizes, int n_in,
                              void* d_out, int out_size, void* d_ws, size_t ws_size,
                              hipStream_t stream)
{
    const float* x      = (const float*)d_in[0];
    const float* coords = (const float*)d_in[1];
    const float* ps     = (const float*)d_in[2];
    const float* pe_w   = (const float*)d_in[3];
    const float* pe_b   = (const float*)d_in[4];
    const float* pe_g   = (const float*)d_in[5];
    const float* pe_bt  = (const float*)d_in[6];
    const float* in_w   = (const float*)d_in[7];
    const float* in_b   = (const float*)d_in[8];
    const float* out_w  = (const float*)d_in[9];
    const float* out_b  = (const float*)d_in[10];
    float* out = (float*)d_out;

    float* ws  = (float*)d_ws;
    float* cxp = ws;            // 2048
    float* cyp = ws + 2048;     // 2048
    float* czp = ws + 4096;     // 2048
    float* qkvb = ws + 6144;    // 2000*384

    prep_qkv_kernel<<<189, 256, 0, stream>>>(x, coords, ps, pe_w, pe_b, pe_g, pe_bt,
                                             in_w, in_b, cxp, cyp, czp, qkvb);
    attn_proj_kernel<<<2000, 256, 0, stream>>>(cxp, cyp, czp, qkvb, out_w, out_b, out);
}